// Round 1
// 757.459 us; speedup vs baseline: 1.4808x; 1.4808x over previous
//
#include <hip/hip_runtime.h>
#include <hip/hip_bf16.h>
#include <stdint.h>

#define N_TOK 8192
#define DIM 1024
#define HID 4096
#define NEXP 8
#define NSLOT 16384  // N_TOK * top_k
#define NBLK 64      // NSLOT / 256

typedef __attribute__((ext_vector_type(8))) __bf16 bf16x8;
typedef __attribute__((ext_vector_type(4))) float f32x4;

__device__ __forceinline__ unsigned short f2bf(float f) {
  unsigned int u = __float_as_uint(f);
  u += 0x7fff + ((u >> 16) & 1);  // round-to-nearest-even
  return (unsigned short)(u >> 16);
}
__device__ __forceinline__ float bf2f(unsigned short s) {
  return __uint_as_float(((unsigned int)s) << 16);
}
__device__ __forceinline__ void async16(const void* g, void* l) {
  __builtin_amdgcn_global_load_lds((__attribute__((address_space(1))) void*)(g),
                                   (__attribute__((address_space(3))) void*)(l), 16, 0, 0);
}

// ---------------- fp32 -> bf16 weight conversion ----------------
__global__ void cvt_kernel(const float* __restrict__ src, unsigned short* __restrict__ dst,
                           int n4) {
  int i = blockIdx.x * 256 + threadIdx.x;
  int stride = gridDim.x * 256;
  for (; i < n4; i += stride) {
    float4 v = ((const float4*)src)[i];
    ushort4 o;
    o.x = f2bf(v.x); o.y = f2bf(v.y); o.z = f2bf(v.z); o.w = f2bf(v.w);
    ((ushort4*)dst)[i] = o;
  }
}

// ---------------- gating: 1 wave per token (no global atomics) ----------------
__global__ void gate_kernel(const float* __restrict__ x, const float* __restrict__ gw,
                            const float* __restrict__ gb, int* __restrict__ expert2,
                            float* __restrict__ score2) {
  int token = blockIdx.x * 4 + (threadIdx.x >> 6);
  int lane = threadIdx.x & 63;
  const float4* xr = (const float4*)(x + (size_t)token * DIM);
  float acc[NEXP];
#pragma unroll
  for (int e = 0; e < NEXP; ++e) acc[e] = 0.f;
#pragma unroll
  for (int it = 0; it < DIM / 4 / 64; ++it) {
    int d = it * 64 + lane;
    float4 xv = xr[d];
#pragma unroll
    for (int e = 0; e < NEXP; ++e) {
      float4 wv = ((const float4*)(gw + e * DIM))[d];
      acc[e] += xv.x * wv.x + xv.y * wv.y + xv.z * wv.z + xv.w * wv.w;
    }
  }
#pragma unroll
  for (int off = 32; off > 0; off >>= 1) {
#pragma unroll
    for (int e = 0; e < NEXP; ++e) acc[e] += __shfl_xor(acc[e], off, 64);
  }
  if (lane == 0) {
    float lg[NEXP], mx = -1e30f;
#pragma unroll
    for (int e = 0; e < NEXP; ++e) { lg[e] = acc[e] + gb[e]; mx = fmaxf(mx, lg[e]); }
    float p[NEXP], s = 0.f;
#pragma unroll
    for (int e = 0; e < NEXP; ++e) { p[e] = expf(lg[e] - mx); s += p[e]; }
    float inv = 1.f / s;
#pragma unroll
    for (int e = 0; e < NEXP; ++e) p[e] *= inv;
    int i0 = 0;
#pragma unroll
    for (int e = 1; e < NEXP; ++e) if (p[e] > p[i0]) i0 = e;
    int i1 = (i0 == 0) ? 1 : 0;
#pragma unroll
    for (int e = 0; e < NEXP; ++e) if (e != i0 && p[e] > p[i1]) i1 = e;
    float eb = expf(p[i1] - p[i0]);  // <= 1
    float dn = 1.f / (1.f + eb);
    expert2[token * 2] = i0;
    expert2[token * 2 + 1] = i1;
    score2[token * 2] = dn;
    score2[token * 2 + 1] = eb * dn;
  }
}

// ---------------- routing: hist -> scan -> assign (LDS atomics only) ----------
__global__ void hist_kernel(const int* __restrict__ expert2, int* __restrict__ hist) {
  __shared__ int lh[NEXP];
  int b = blockIdx.x, t = threadIdx.x;
  if (t < NEXP) lh[t] = 0;
  __syncthreads();
  atomicAdd(&lh[expert2[b * 256 + t]], 1);
  __syncthreads();
  if (t < NEXP) hist[b * NEXP + t] = lh[t];
}

__global__ void scan_kernel(const int* __restrict__ hist, int* __restrict__ cnt,
                            int* __restrict__ off_, int* __restrict__ base) {
  __shared__ int lh[NBLK * NEXP];
  __shared__ int ltot[NEXP];
  __shared__ int loff[NEXP];
  int t = threadIdx.x;  // 64 threads
#pragma unroll
  for (int e = 0; e < NEXP; ++e) lh[t * NEXP + e] = hist[t * NEXP + e];
  __syncthreads();
  if (t < NEXP) {
    int s = 0;
    for (int b = 0; b < NBLK; ++b) { int v = lh[b * NEXP + t]; lh[b * NEXP + t] = s; s += v; }
    ltot[t] = s;
  }
  __syncthreads();
  if (t == 0) {
    int s = 0;
#pragma unroll
    for (int e = 0; e < NEXP; ++e) { loff[e] = s; s += ltot[e]; }
  }
  __syncthreads();
  if (t < NEXP) { cnt[t] = ltot[t]; off_[t] = loff[t]; }
#pragma unroll
  for (int e = 0; e < NEXP; ++e) base[t * NEXP + e] = loff[e] + lh[t * NEXP + e];
}

__global__ void assign_kernel(const int* __restrict__ expert2, const int* __restrict__ base,
                              int* __restrict__ slot_of, int* __restrict__ token_of) {
  __shared__ int lh[NEXP];
  int b = blockIdx.x, t = threadIdx.x;
  if (t < NEXP) lh[t] = 0;
  __syncthreads();
  int i = b * 256 + t;
  int e = expert2[i];
  int r = atomicAdd(&lh[e], 1);
  int slot = base[b * NEXP + e] + r;
  slot_of[i] = slot;
  token_of[slot] = i >> 1;
}

__global__ void gather_kernel(const float* __restrict__ x, const int* __restrict__ token_of,
                              unsigned short* __restrict__ xg) {
  int slot = blockIdx.x;
  int t = threadIdx.x;
  int n = token_of[slot];
  float4 v = *(const float4*)(x + (size_t)n * DIM + t * 4);
  ushort4 o;
  o.x = f2bf(v.x); o.y = f2bf(v.y); o.z = f2bf(v.z); o.w = f2bf(v.w);
  *(ushort4*)(xg + (size_t)slot * DIM + t * 4) = o;
}

// ------- bf16 MFMA GEMM, XCD-swizzled panels, coalesced+swizzled staging -------
// C[m][n] = sum_k A[m][k] * B[n][k]  (+bias, optional relu), rows = expert slots.
// 128x128 tile, BK=64, 4 waves each 64x64 via 4x4 mfma_16x16x32.
// Grid: (8, NB_M, NPANEL/8); panel = z*8+x -> all m-blocks of a B-panel on one
// XCD (B L2-hot).
//
// Round-4 change (theory: TA/L2 request serialization, MfmaUtil 13.7%):
// old staging put a wave's 64 lanes at 64 different rows (8KB stride, 16B each)
// -> ~64 line transactions per global_load_lds, ~2K cyc/iter of pure request
// issue. New staging is K-contiguous: c=i*256+tid, row=c>>3, kc=c&7 -> a wave
// covers 8 rows x 128B contiguous (~16 lines/instr, 4x fewer). The resulting
// row-major [128][64] LDS tile would be a stride-128B bank disaster on
// ds_read_b128, so apply the both-sides XOR swizzle (guide rule #21):
// linear LDS dest + pre-swizzled global source chunk (kc ^ (row&7)) + same XOR
// on the read address. Bank spread: chunk slot (s*4+quad)^(l16&7) -> 2
// lanes/bank (free, m136).
// Also: single LDS buffer (32KB) instead of 64KB dbuf -> 4-5 blocks/CU; rely on
// inter-block overlap (m97 structure, m99/m100: explicit dbuf buys nothing).
template <int KLEN, int NLEN, bool RELU, bool BCVT>
__global__ __launch_bounds__(256, 4) void gemm_bt(
    const unsigned short* __restrict__ A, const void* __restrict__ Bptr,
    const float* __restrict__ bias, unsigned short* __restrict__ C,
    const int* __restrict__ cnt, const int* __restrict__ off_) {
  const int NB_N = NLEN / 128;
  int panel = blockIdx.z * 8 + blockIdx.x;
  int e = panel / NB_N;
  int n0 = (panel % NB_N) * 128;
  int me = cnt[e];
  int m0 = blockIdx.y * 128;
  if (m0 >= me) return;
  int rb = off_[e] + m0;  // global slot row base

  __shared__ unsigned short lA[8192];  // 16 KB, [row][kc ^ (row&7)] 16B chunks
  __shared__ unsigned short lB[8192];  // 16 KB

  int tid = threadIdx.x;
  int wave = tid >> 6, lane = tid & 63;
  int wm = (wave >> 1) * 64, wn = (wave & 1) * 64;
  int quad = lane >> 4, l16 = lane & 15;
  int x7 = l16 & 7;  // read-side swizzle key (r&7 == l16&7 for all fragment rows)

  // per-thread staging coordinates: 4 chunks of 16B per thread per operand
  // chunk c = i*256+tid; row = c>>3 (8 consecutive rows per wave-instr),
  // kc = c&7; source chunk = kc ^ (row&7)  (XOR involution, matches read side)
  int arow[4], brow[4], akx[4], ldst[4];
#pragma unroll
  for (int i = 0; i < 4; ++i) {
    int c = i * 256 + tid;
    int row = c >> 3;
    akx[i] = (c & 7) ^ (row & 7);
    ldst[i] = c * 8;  // LDS dest in shorts (linear: required by global_load_lds)
    brow[i] = row;
    int grow = rb + row;
    arow[i] = (grow > NSLOT - 1) ? (NSLOT - 1) : grow;  // clamp; rows>=me never stored
  }

  f32x4 acc[4][4];
#pragma unroll
  for (int i = 0; i < 4; ++i)
#pragma unroll
    for (int j = 0; j < 4; ++j) acc[i][j] = {0.f, 0.f, 0.f, 0.f};

  const unsigned short* Bb = (const unsigned short*)Bptr + (size_t)e * NLEN * KLEN;
  const float* Bf = (const float*)Bptr + (size_t)e * NLEN * KLEN;

  for (int k0 = 0; k0 < KLEN; k0 += 64) {
    // ---- stage tile k0 (coalesced: 8 rows x 128B contiguous per wave-instr) ----
#pragma unroll
    for (int i = 0; i < 4; ++i)
      async16(A + (size_t)arow[i] * KLEN + k0 + akx[i] * 8, &lA[ldst[i]]);
    if (BCVT) {
#pragma unroll
      for (int i = 0; i < 4; ++i)
        async16(Bb + (size_t)(n0 + brow[i]) * KLEN + k0 + akx[i] * 8, &lB[ldst[i]]);
    } else {
#pragma unroll
      for (int i = 0; i < 4; ++i) {
        const float* gp = Bf + (size_t)(n0 + brow[i]) * KLEN + k0 + akx[i] * 8;
        float4 v0 = *(const float4*)gp;
        float4 v1 = *(const float4*)(gp + 4);
        union { unsigned short u[8]; bf16x8 v; } pk;
        pk.u[0] = f2bf(v0.x); pk.u[1] = f2bf(v0.y); pk.u[2] = f2bf(v0.z); pk.u[3] = f2bf(v0.w);
        pk.u[4] = f2bf(v1.x); pk.u[5] = f2bf(v1.y); pk.u[6] = f2bf(v1.z); pk.u[7] = f2bf(v1.w);
        *(bf16x8*)(&lB[ldst[i]]) = pk.v;
      }
    }
    __syncthreads();  // drains async16 (vmcnt 0) + ds_writes
    // ---- compute ----
#pragma unroll
    for (int s = 0; s < 2; ++s) {
      int qx = (s * 4 + quad) ^ x7;  // swizzled chunk slot within row
      bf16x8 af[4], bfr[4];
#pragma unroll
      for (int mt = 0; mt < 4; ++mt)
        af[mt] = *(const bf16x8*)(&lA[(wm + mt * 16 + l16) * 64 + qx * 8]);
#pragma unroll
      for (int nt = 0; nt < 4; ++nt)
        bfr[nt] = *(const bf16x8*)(&lB[(wn + nt * 16 + l16) * 64 + qx * 8]);
#pragma unroll
      for (int mt = 0; mt < 4; ++mt)
#pragma unroll
        for (int nt = 0; nt < 4; ++nt)
          acc[mt][nt] =
              __builtin_amdgcn_mfma_f32_16x16x32_bf16(af[mt], bfr[nt], acc[mt][nt], 0, 0, 0);
    }
    __syncthreads();  // all ds_reads done before next stage overwrites
  }
  // epilogue: C/D layout col = lane&15, row = quad*4 + reg  (m89-verified)
#pragma unroll
  for (int mt = 0; mt < 4; ++mt) {
#pragma unroll
    for (int r = 0; r < 4; ++r) {
      int mrow = wm + mt * 16 + quad * 4 + r;
      if (m0 + mrow < me) {
#pragma unroll
        for (int nt = 0; nt < 4; ++nt) {
          int col = n0 + wn + nt * 16 + l16;
          float v = acc[mt][nt][r] + bias[e * NLEN + col];
          if (RELU) v = fmaxf(v, 0.f);
          C[(size_t)(rb + mrow) * NLEN + col] = f2bf(v);
        }
      }
    }
  }
}

// ---------------- combine + residual + LayerNorm ----------------
__global__ void ln_kernel(const float* __restrict__ x, const unsigned short* __restrict__ y,
                          const int* __restrict__ slot_of, const float* __restrict__ score2,
                          const float* __restrict__ lnw, const float* __restrict__ lnb,
                          float* __restrict__ out) {
  __shared__ float red[8];
  int n = blockIdx.x, t = threadIdx.x;
  int wave = t >> 6, lane = t & 63;
  int s0 = slot_of[n * 2], s1 = slot_of[n * 2 + 1];
  float w0 = score2[n * 2], w1 = score2[n * 2 + 1];
  float4 xv = *(const float4*)(x + (size_t)n * DIM + t * 4);
  ushort4 y0 = *(const ushort4*)(y + (size_t)s0 * DIM + t * 4);
  ushort4 y1 = *(const ushort4*)(y + (size_t)s1 * DIM + t * 4);
  float r0 = xv.x + w0 * bf2f(y0.x) + w1 * bf2f(y1.x);
  float r1 = xv.y + w0 * bf2f(y0.y) + w1 * bf2f(y1.y);
  float r2 = xv.z + w0 * bf2f(y0.z) + w1 * bf2f(y1.z);
  float r3 = xv.w + w0 * bf2f(y0.w) + w1 * bf2f(y1.w);
  float sum = r0 + r1 + r2 + r3;
  float sq = r0 * r0 + r1 * r1 + r2 * r2 + r3 * r3;
#pragma unroll
  for (int off = 32; off > 0; off >>= 1) {
    sum += __shfl_xor(sum, off, 64);
    sq += __shfl_xor(sq, off, 64);
  }
  if (lane == 0) { red[wave] = sum; red[4 + wave] = sq; }
  __syncthreads();
  sum = red[0] + red[1] + red[2] + red[3];
  sq = red[4] + red[5] + red[6] + red[7];
  float mu = sum * (1.f / DIM);
  float var = sq * (1.f / DIM) - mu * mu;
  float rs = rsqrtf(var + 1e-5f);
  float4 wv = *(const float4*)(lnw + t * 4);
  float4 bv = *(const float4*)(lnb + t * 4);
  float4 o;
  o.x = (r0 - mu) * rs * wv.x + bv.x;
  o.y = (r1 - mu) * rs * wv.y + bv.y;
  o.z = (r2 - mu) * rs * wv.z + bv.z;
  o.w = (r3 - mu) * rs * wv.w + bv.w;
  *(float4*)(out + (size_t)n * DIM + t * 4) = o;
}

// ---------------- launch ----------------
extern "C" void kernel_launch(void* const* d_in, const int* in_sizes, int n_in,
                              void* d_out, int out_size, void* d_ws, size_t ws_size,
                              hipStream_t stream) {
  const float* x = (const float*)d_in[0];
  const float* gw = (const float*)d_in[1];
  const float* gb = (const float*)d_in[2];
  const float* w1 = (const float*)d_in[3];
  const float* b1 = (const float*)d_in[4];
  const float* w2 = (const float*)d_in[5];
  const float* b2 = (const float*)d_in[6];
  const float* lnw = (const float*)d_in[7];
  const float* lnb = (const float*)d_in[8];
  float* out = (float*)d_out;
  char* ws = (char*)d_ws;

  int* cnt = (int*)(ws + 0);
  int* off_ = (int*)(ws + 64);
  int* hist = (int*)(ws + 4096);             // 64*8 ints
  int* base = (int*)(ws + 4096 + 2048);      // 64*8 ints
  int* expert2 = (int*)(ws + 65536);         // 16384 ints
  float* score2 = (float*)(ws + 2 * 65536);  // 16384 floats
  int* slot_of = (int*)(ws + 3 * 65536);     // 16384 ints
  int* token_of = (int*)(ws + 4 * 65536);    // 16384 ints
  const size_t XG_OFF = 524288;                           // 16384x1024 bf16 = 32 MB
  const size_t H_OFF = XG_OFF + (size_t)NSLOT * DIM * 2;  // 16384x4096 bf16 = 128 MB
  const size_t Y_OFF = H_OFF + (size_t)NSLOT * HID * 2;   // 16384x1024 bf16 = 32 MB
  const size_t WB1_OFF = Y_OFF + (size_t)NSLOT * DIM * 2;         // 64 MB
  const size_t WB2_OFF = WB1_OFF + (size_t)NEXP * HID * DIM * 2;  // 64 MB
  const size_t WS_NEED = WB2_OFF + (size_t)NEXP * DIM * HID * 2;
  unsigned short* xg = (unsigned short*)(ws + XG_OFF);
  unsigned short* h = (unsigned short*)(ws + H_OFF);
  unsigned short* y = (unsigned short*)(ws + Y_OFF);
  unsigned short* wb1 = (unsigned short*)(ws + WB1_OFF);
  unsigned short* wb2 = (unsigned short*)(ws + WB2_OFF);
  bool cvt_ok = ws_size >= WS_NEED;

  gate_kernel<<<N_TOK / 4, 256, 0, stream>>>(x, gw, gb, expert2, score2);
  hist_kernel<<<NBLK, 256, 0, stream>>>(expert2, hist);
  scan_kernel<<<1, 64, 0, stream>>>(hist, cnt, off_, base);
  assign_kernel<<<NBLK, 256, 0, stream>>>(expert2, base, slot_of, token_of);
  gather_kernel<<<NSLOT, 256, 0, stream>>>(x, token_of, xg);
  if (cvt_ok) {
    const int n4 = NEXP * HID * DIM / 4;
    cvt_kernel<<<4096, 256, 0, stream>>>(w1, wb1, n4);
    cvt_kernel<<<4096, 256, 0, stream>>>(w2, wb2, n4);
    gemm_bt<DIM, HID, true, true>
        <<<dim3(8, 128, (NEXP * HID / 128) / 8), 256, 0, stream>>>(xg, wb1, b1, h, cnt, off_);
    gemm_bt<HID, DIM, false, true>
        <<<dim3(8, 128, (NEXP * DIM / 128) / 8), 256, 0, stream>>>(h, wb2, b2, y, cnt, off_);
  } else {
    gemm_bt<DIM, HID, true, false>
        <<<dim3(8, 128, (NEXP * HID / 128) / 8), 256, 0, stream>>>(xg, w1, b1, h, cnt, off_);
    gemm_bt<HID, DIM, false, false>
        <<<dim3(8, 128, (NEXP * DIM / 128) / 8), 256, 0, stream>>>(h, w2, b2, y, cnt, off_);
  }
  ln_kernel<<<N_TOK, 256, 0, stream>>>(x, y, slot_of, score2, lnw, lnb, out);
}